// Round 4
// baseline (2127.341 us; speedup 1.0000x reference)
//
#include <hip/hip_runtime.h>
#include <math.h>

#define BB 4
#define TT 16
#define N_TOK 1024
#define DD 768
#define K_KEEP 64
#define G_GLOB 4
#define H_HEADS 8
#define HDIM 96
#define BT (BB*TT)              /* 64  */
#define NTOT (BT*N_TOK)         /* 65536 */
#define DH (DD/2)               /* 384 */
#define HG (H_HEADS*G_GLOB)     /* 32  */

// ---------------------------------------------------------------- K0: q0 = global_tokens @ wq + bq  [4,768]
__global__ void k_prep_q(const float* __restrict__ gt, const float* __restrict__ wq,
                         const float* __restrict__ bq, float* __restrict__ q0) {
    int idx = blockIdx.x * 256 + threadIdx.x;      // 0..3071
    int g = idx / DD, e = idx % DD;
    float acc = bq[e];
    const float* gr = gt + g * DD;
    for (int d = 0; d < DD; ++d) acc = fmaf(gr[d], wq[(size_t)d * DD + e], acc);
    q0[idx] = acc;
}

// ---------------------------------------------------------------- K1: U[d][hg] = scale * wk[d,hslice]·q0[g,hslice]; c[hg]
__global__ void k_prep_u(const float* __restrict__ wk, const float* __restrict__ bk,
                         const float* __restrict__ q0, float* __restrict__ U,
                         float* __restrict__ cvec) {
    int idx = blockIdx.x * 256 + threadIdx.x;      // 0..24575
    int d = idx / HG, hg = idx % HG;
    int h = hg >> 2, g = hg & 3;
    const float scale = 1.0f / sqrtf((float)HDIM);
    const float* wr = wk + (size_t)d * DD + h * HDIM;
    const float* qr = q0 + g * DD + h * HDIM;
    float acc = 0.f;
    for (int e = 0; e < HDIM; ++e) acc = fmaf(wr[e], qr[e], acc);
    U[idx] = acc * scale;
    if (blockIdx.x == 0 && threadIdx.x < HG) {
        int h2 = threadIdx.x >> 2, g2 = threadIdx.x & 3;
        const float* br = bk + h2 * HDIM;
        const float* q2 = q0 + g2 * DD + h2 * HDIM;
        float a2 = 0.f;
        for (int e = 0; e < HDIM; ++e) a2 = fmaf(br[e], q2[e], a2);
        cvec[threadIdx.x] = a2 * scale;
    }
}

// ---------------------------------------------------------------- K2: fused scorer + attention logits
// Scorer path emulates numpy c_einsum fp32 semantics EXACTLY for the first
// einsum: per output element, sequential ascending-d accumulation with
// separately-rounded mul then add (NO FMA) in fp32, then +b1 in fp32.
// Everything downstream (gelu erf, dot w2, +b2, roi bias) in float64, which
// matches the NEP50 float64-promotion path and is within ~1e-8 of the
// all-fp32 path. fp64 scores go to scores_d for the sort. Logits path fp32.
__global__ __launch_bounds__(256) void k_score_logits(
        const float* __restrict__ tokens, const int* __restrict__ roi,
        const float* __restrict__ w1, const float* __restrict__ b1,
        const float* __restrict__ w2, const float* __restrict__ b2,
        const float* __restrict__ U, const float* __restrict__ cvec,
        float* __restrict__ out_scores, double* __restrict__ scores_d,
        float* __restrict__ logits) {
    __shared__ float stok[16 * DD];                // 48 KB
    int blk = blockIdx.x, tid = threadIdx.x;
    {
        const float4* t4 = (const float4*)(tokens + (size_t)blk * 16 * DD);
        float4* s4 = (float4*)stok;
#pragma unroll
        for (int r = 0; r < 12; ++r) s4[r * 256 + tid] = t4[r * 256 + tid];
    }
    __syncthreads();
    int tx = tid & 63, ty = tid >> 6;

    float acc[6][4];
#pragma unroll
    for (int j = 0; j < 6; ++j)
#pragma unroll
        for (int i = 0; i < 4; ++i) acc[j][i] = 0.f;
    float accL[4] = {0.f, 0.f, 0.f, 0.f};

    const float* s0 = stok + ty * DD;
#pragma unroll 2
    for (int d = 0; d < DD; ++d) {
        float tv0 = s0[d], tv1 = s0[4 * DD + d], tv2 = s0[8 * DD + d], tv3 = s0[12 * DD + d];
        const float* wr = w1 + (size_t)d * DH + tx;
        float wu = 0.f;
        if (tx < HG) wu = U[d * HG + tx];
#pragma unroll
        for (int j = 0; j < 6; ++j) {
            float w = wr[64 * j];
            // numpy c_einsum fp32: round(mul) then round(add), sequential in d
            acc[j][0] = __fadd_rn(acc[j][0], __fmul_rn(w, tv0));
            acc[j][1] = __fadd_rn(acc[j][1], __fmul_rn(w, tv1));
            acc[j][2] = __fadd_rn(acc[j][2], __fmul_rn(w, tv2));
            acc[j][3] = __fadd_rn(acc[j][3], __fmul_rn(w, tv3));
        }
        accL[0] = fmaf(wu, tv0, accL[0]);
        accL[1] = fmaf(wu, tv1, accL[1]);
        accL[2] = fmaf(wu, tv2, accL[2]);
        accL[3] = fmaf(wu, tv3, accL[3]);
    }

    // ---- scorer epilogue: x = fp32(pre + b1); then float64 gelu + dot(w2)
    double p[4] = {0.0, 0.0, 0.0, 0.0};
    const double inv_sqrt2 = 0.70710678118654752440;
#pragma unroll
    for (int j = 0; j < 6; ++j) {
        int col = tx + 64 * j;
        float bb = b1[col];
        double ww2 = (double)w2[col];
#pragma unroll
        for (int i = 0; i < 4; ++i) {
            float xf = __fadd_rn(acc[j][i], bb);           // fp32 like np
            double x = (double)xf;
            double hd = 0.5 * x * (1.0 + erf(x * inv_sqrt2));
            p[i] = fma(hd, ww2, p[i]);
        }
    }
#pragma unroll
    for (int i = 0; i < 4; ++i)
#pragma unroll
        for (int off = 32; off; off >>= 1) p[i] += __shfl_xor(p[i], off);

    double b2v = (double)b2[0];
    if (tx == 0) {
#pragma unroll
        for (int i = 0; i < 4; ++i) {
            int t = ty + 4 * i;
            int gtok = blk * 16 + t;
            double s = (p[i] + b2v) * (roi[gtok] ? 2.0 : 1.0);
            out_scores[gtok] = (float)s;
            scores_d[gtok] = s;
        }
    }
    // ---- logits write: [bt][hg][n]
    if (tx < HG) {
        float cv = cvec[tx];
        int bt = (blk * 16) / N_TOK;
        int n0 = (blk * 16) % N_TOK;
#pragma unroll
        for (int i = 0; i < 4; ++i) {
            int t = ty + 4 * i;
            logits[((size_t)bt * HG + tx) * N_TOK + n0 + t] = accL[i] + cv;
        }
    }
}

// ---------------------------------------------------------------- K3: exact top-64 of 1024 on FP64 scores
// (bitonic full sort, desc value, asc index tiebreak — matches lax.top_k)
__global__ void k_topk(const double* __restrict__ scores_d, float* __restrict__ out_idx_f,
                       int* __restrict__ idx_ws) {
    __shared__ double sv[1024];                    // 8 KB
    __shared__ int    si[1024];                    // 4 KB
    int bt = blockIdx.x, tid = threadIdx.x;
#pragma unroll
    for (int r = 0; r < 4; ++r) {
        int i = r * 256 + tid;
        sv[i] = scores_d[(size_t)bt * 1024 + i];
        si[i] = i;
    }
    __syncthreads();
    for (int k = 2; k <= 1024; k <<= 1) {
        for (int j = k >> 1; j > 0; j >>= 1) {
#pragma unroll
            for (int r = 0; r < 4; ++r) {
                int i = r * 256 + tid;
                int ixj = i ^ j;
                if (ixj > i) {
                    bool dir = ((i & k) == 0);
                    double va = sv[i], vb = sv[ixj];
                    int ia = si[i], ib = si[ixj];
                    bool lt_ab = (va > vb) || (va == vb && ia < ib);
                    bool lt_ba = (vb > va) || (vb == va && ib < ia);
                    bool sw = dir ? lt_ba : lt_ab;
                    if (sw) { sv[i] = vb; sv[ixj] = va; si[i] = ib; si[ixj] = ia; }
                }
            }
            __syncthreads();
        }
    }
    if (tid < K_KEEP) {
        int v = si[tid];
        out_idx_f[bt * K_KEEP + tid] = (float)v;
        idx_ws[bt * K_KEEP + tid] = v;
    }
}

// ---------------------------------------------------------------- K4: gather selected tokens -> selected + compressed[:, :64]
__global__ void k_gather(const float* __restrict__ tokens, const int* __restrict__ idx_ws,
                         float* __restrict__ out_sel, float* __restrict__ out_comp) {
    int blk = blockIdx.x;                  // 64*64
    int bt = blk >> 6, kk = blk & 63;
    int src = bt * N_TOK + idx_ws[bt * K_KEEP + kk];
    const float4* s = (const float4*)(tokens + (size_t)src * DD);
    float4 v = s[threadIdx.x];             // 192 threads * float4 = 768
    ((float4*)(out_sel + ((size_t)bt * K_KEEP + kk) * DD))[threadIdx.x] = v;
    ((float4*)(out_comp + ((size_t)bt * (K_KEEP + G_GLOB) + kk) * DD))[threadIdx.x] = v;
}

// ---------------------------------------------------------------- K5: softmax over n (rows of 1024), in place
__global__ void k_softmax(float* __restrict__ logits) {
    size_t row = blockIdx.x;
    float* p = logits + row * 1024;
    int tid = threadIdx.x;
    float4 v = ((float4*)p)[tid];
    float m = fmaxf(fmaxf(v.x, v.y), fmaxf(v.z, v.w));
#pragma unroll
    for (int off = 32; off; off >>= 1) m = fmaxf(m, __shfl_xor(m, off));
    __shared__ float red[4];
    int wid = tid >> 6;
    if ((tid & 63) == 0) red[wid] = m;
    __syncthreads();
    m = fmaxf(fmaxf(red[0], red[1]), fmaxf(red[2], red[3]));
    float e0 = expf(v.x - m), e1 = expf(v.y - m), e2 = expf(v.z - m), e3 = expf(v.w - m);
    float s = (e0 + e1) + (e2 + e3);
#pragma unroll
    for (int off = 32; off; off >>= 1) s += __shfl_xor(s, off);
    __syncthreads();
    if ((tid & 63) == 0) red[wid] = s;
    __syncthreads();
    float tot = (red[0] + red[1]) + (red[2] + red[3]);
    float inv = 1.0f / tot;
    v.x = e0 * inv; v.y = e1 * inv; v.z = e2 * inv; v.w = e3 * inv;
    ((float4*)p)[tid] = v;
}

// ---------------------------------------------------------------- K6: wsums[bt][hg][d] = sum_n attn[bt][hg][n] * tokens[bt][n][d]
__global__ void k_wsum(const float* __restrict__ tokens, const float* __restrict__ attn,
                       float* __restrict__ wsums) {
    int bt = blockIdx.x / 3, dc = blockIdx.x % 3;
    int d0 = dc * 256, tid = threadIdx.x;
    __shared__ float sat[128][HG];         // 16 KB, [x][hg]
    float acc[HG];
#pragma unroll
    for (int q = 0; q < HG; ++q) acc[q] = 0.f;
    for (int nc = 0; nc < 8; ++nc) {
        __syncthreads();
#pragma unroll
        for (int r = 0; r < 16; ++r) {
            int e = r * 256 + tid;         // 0..4095
            int hg = e & 31, x = e >> 5;   // conflict-free LDS writes
            sat[x][hg] = attn[((size_t)bt * HG + hg) * N_TOK + nc * 128 + x];
        }
        __syncthreads();
        const float* tb = tokens + ((size_t)bt * N_TOK + nc * 128) * DD + d0 + tid;
        for (int x = 0; x < 128; ++x) {
            float tv = tb[(size_t)x * DD];
#pragma unroll
            for (int q8 = 0; q8 < 8; ++q8) {
                float4 a4 = *(const float4*)&sat[x][q8 * 4];   // broadcast
                acc[q8 * 4 + 0] = fmaf(a4.x, tv, acc[q8 * 4 + 0]);
                acc[q8 * 4 + 1] = fmaf(a4.y, tv, acc[q8 * 4 + 1]);
                acc[q8 * 4 + 2] = fmaf(a4.z, tv, acc[q8 * 4 + 2]);
                acc[q8 * 4 + 3] = fmaf(a4.w, tv, acc[q8 * 4 + 3]);
            }
        }
    }
#pragma unroll
    for (int q = 0; q < HG; ++q)
        wsums[((size_t)bt * HG + q) * DD + d0 + tid] = acc[q];
}

// ---------------------------------------------------------------- K7: ctx = wsums@wv + bv ; global_out = ctx@wo + bo
__global__ void k_ctx_out(const float* __restrict__ wsums, const float* __restrict__ wv,
                          const float* __restrict__ bv, const float* __restrict__ wo,
                          const float* __restrict__ bo, float* __restrict__ o_go,
                          float* __restrict__ o_comp) {
    int bt = blockIdx.x, tid = threadIdx.x;
    __shared__ float sctx[G_GLOB][DD];     // 12 KB
#pragma unroll
    for (int r = 0; r < 3; ++r) {
        int e = r * 256 + tid;
        int h = e / HDIM;
        float a[4];
#pragma unroll
        for (int g = 0; g < 4; ++g) a[g] = bv[e];
        const float* wcol = wv + e;
        for (int d = 0; d < DD; ++d) {
            float wvd = wcol[(size_t)d * DD];
#pragma unroll
            for (int g = 0; g < 4; ++g)
                a[g] = fmaf(wsums[((size_t)bt * HG + h * 4 + g) * DD + d], wvd, a[g]);
        }
#pragma unroll
        for (int g = 0; g < 4; ++g) sctx[g][e] = a[g];
    }
    __syncthreads();
#pragma unroll
    for (int r = 0; r < 3; ++r) {
        int e = r * 256 + tid;
        float a[4];
#pragma unroll
        for (int g = 0; g < 4; ++g) a[g] = bo[e];
        const float* wcol = wo + e;
        for (int d = 0; d < DD; ++d) {
            float wod = wcol[(size_t)d * DD];
#pragma unroll
            for (int g = 0; g < 4; ++g) a[g] = fmaf(sctx[g][d], wod, a[g]);
        }
#pragma unroll
        for (int g = 0; g < 4; ++g) {
            o_go[((size_t)bt * G_GLOB + g) * DD + e] = a[g];
            o_comp[((size_t)bt * (K_KEEP + G_GLOB) + K_KEEP + g) * DD + e] = a[g];
        }
    }
}

// ================================================================ launch
extern "C" void kernel_launch(void* const* d_in, const int* in_sizes, int n_in,
                              void* d_out, int out_size, void* d_ws, size_t ws_size,
                              hipStream_t stream) {
    const float* tokens = (const float*)d_in[0];
    const int*   roi    = (const int*)d_in[1];
    const float* w1     = (const float*)d_in[2];
    const float* b1     = (const float*)d_in[3];
    const float* w2     = (const float*)d_in[4];
    const float* b2     = (const float*)d_in[5];
    const float* gt     = (const float*)d_in[6];
    const float* wq     = (const float*)d_in[7];
    const float* bq     = (const float*)d_in[8];
    const float* wk     = (const float*)d_in[9];
    const float* bk     = (const float*)d_in[10];
    const float* wv     = (const float*)d_in[11];
    const float* bv     = (const float*)d_in[12];
    const float* wo     = (const float*)d_in[13];
    const float* bo     = (const float*)d_in[14];

    float* out = (float*)d_out;
    float* ws  = (float*)d_ws;

    // workspace layout (floats)
    float*  q0     = ws;                 // 3072
    float*  U      = ws + 3072;          // 24576
    float*  cvec   = ws + 27648;         // 32
    int*    tki    = (int*)(ws + 27680); // 4096 ints
    float*  logits = ws + 32768;         // 2,097,152  (becomes attn in place)
    float*  wsums  = ws + 2129920;       // 1,572,864
    double* scrd   = (double*)(ws + 3702784); // 65,536 doubles (byte off 14,811,136, 8-aligned)

    // output layout (floats, tuple order)
    float* o_comp = out;                // [64][68][768]
    float* o_sel  = out + 3342336;      // [64][64][768]
    float* o_go   = out + 6488064;      // [64][4][768]
    float* o_idx  = out + 6684672;      // [64][64] as float
    float* o_sc   = out + 6688768;      // [64][1024]

    k_prep_q      <<<dim3(12),   dim3(256), 0, stream>>>(gt, wq, bq, q0);
    k_prep_u      <<<dim3(96),   dim3(256), 0, stream>>>(wk, bk, q0, U, cvec);
    k_score_logits<<<dim3(4096), dim3(256), 0, stream>>>(tokens, roi, w1, b1, w2, b2,
                                                         U, cvec, o_sc, scrd, logits);
    k_topk        <<<dim3(64),   dim3(256), 0, stream>>>(scrd, o_idx, tki);
    k_gather      <<<dim3(4096), dim3(192), 0, stream>>>(tokens, tki, o_sel, o_comp);
    k_softmax     <<<dim3(2048), dim3(256), 0, stream>>>(logits);
    k_wsum        <<<dim3(192),  dim3(256), 0, stream>>>(tokens, logits, wsums);
    k_ctx_out     <<<dim3(64),   dim3(256), 0, stream>>>(wsums, wv, bv, wo, bo, o_go, o_comp);
}